// Round 6
// baseline (644.257 us; speedup 1.0000x reference)
//
#include <hip/hip_runtime.h>
#include <hip/hip_cooperative_groups.h>
#include <math.h>

namespace cg = cooperative_groups;

#define D 512
#define C 17
#define CAP 2048      // per-class selected-list capacity (= filter_K)
#define CANDCAP 2048  // per-class boundary-bucket candidate capacity
#define PAD 64        // counter padding stride (ints) -> 256 B apart
#define GRID 256      // cooperative grid: 1 block/CU

// ---------------------------------------------------------------------------
// in-wave helper: given 4 bins/lane (h[0..3]) find the bin where the running
// cumulative count crosses rank K. Broadcasts (bin, excl, total).
// ---------------------------------------------------------------------------
__device__ inline void wave_rank256(const unsigned h[4], int K, int lane,
                                    int* out_bin, int* out_excl, unsigned* out_total)
{
    unsigned lsum = h[0] + h[1] + h[2] + h[3];
    unsigned x = lsum;
    for (int off = 1; off < 64; off <<= 1) {
        unsigned t = __shfl_up(x, off, 64);
        if (lane >= off) x += t;
    }
    *out_total = __shfl((int)x, 63, 64);
    unsigned excl = x - lsum;
    int myb = -1; int mye = 0;
    unsigned run = excl;
    for (int k = 0; k < 4; ++k) {
        unsigned inc = run + h[k];
        if ((int)run < K && K <= (int)inc) { myb = lane * 4 + k; mye = (int)run; }
        run = inc;
    }
    unsigned long long m = __ballot(myb >= 0);
    int src = (int)__ffsll((unsigned long long)m) - 1;
    *out_bin  = __shfl(myb, src, 64);
    *out_excl = __shfl(mye, src, 64);
}

// ===========================================================================
// =====================  COOPERATIVE SINGLE-KERNEL PATH  ====================
// ===========================================================================
struct KParams {
    const float* feature; const float* clf_w; const float* clf_b;
    const float* supports; const float* ent_bank; const int* labels;
    const int* fk;
    float* ent_new; int* yhat;
    unsigned* hist16; unsigned* ghist8; float* Wc;
    int* cnt_g; unsigned* ccnt_g; int* krem_g; int* s2cnt;
    int* list; int* list2; unsigned* candb; int* candi;
    float* out; int N; int B;
};

union SMem {
    struct { unsigned h8[C * 256]; } p1;                        // 17.4 KB
    struct { unsigned pfx16[C]; int krem_s[C]; int done_s[C];
             int lcnt[C]; int lofs[C]; int lput[C]; int gbase[C];
             int l_list[1312]; } p2;                            // ~5.7 KB
    struct { unsigned cb[CANDCAP]; int ci[CANDCAP]; } p3;       // 16.4 KB
    struct { float wsum[4][D]; } p4;                            // 8.2 KB
    struct { float w_s[9 * D]; float inv_s[32]; } p5;           // 18.6 KB
};

__global__ __launch_bounds__(256, 1) void k_fused(KParams P)
{
    cg::grid_group grid = cg::this_grid();
    __shared__ SMem sm;

    const int tid = threadIdx.x, bid = blockIdx.x;
    const int gtid = bid * 256 + tid;
    const int gsz = GRID * 256;
    const int wave = tid >> 6, lane = tid & 63;
    const int gwave = bid * 4 + wave, nwave = GRID * 4;
    const int N = P.N, B = P.B, NT = N + B;

    // ================= P1: classify batch + histograms =====================
    {
        for (int i = tid; i < C * 256; i += 256) sm.p1.h8[i] = 0;
        __syncthreads();

        // classify: one batch row per wave (weights straight from L2)
        for (int row = gwave; row < B; row += nwave) {
            const float* f = P.feature + (size_t)row * D;
            float4 f0 = *(const float4*)(f + lane * 8);
            float4 f1 = *(const float4*)(f + lane * 8 + 4);
            double p[C];
            for (int c = 0; c < C; ++c) {
                const float* w = P.clf_w + c * D + lane * 8;
                double s = (double)f0.x * w[0] + (double)f0.y * w[1] +
                           (double)f0.z * w[2] + (double)f0.w * w[3] +
                           (double)f1.x * w[4] + (double)f1.y * w[5] +
                           (double)f1.z * w[6] + (double)f1.w * w[7];
                for (int m = 32; m; m >>= 1) s += __shfl_xor(s, m, 64);
                p[c] = s + (double)P.clf_b[c];
            }
            if (lane == 0) {
                double mx = p[0]; int am = 0;
                for (int c = 1; c < C; ++c) if (p[c] > mx) { mx = p[c]; am = c; }
                double Z = 0.0, S = 0.0;
                for (int c = 0; c < C; ++c) {
                    double e = exp(p[c] - mx);
                    Z += e; S += e * (p[c] - mx);
                }
                float ent = (float)(log(Z) - S / Z);   // >= 0 always
                P.ent_new[row] = ent;
                P.yhat[row] = am;
                unsigned b = __float_as_uint(ent);
                atomicAdd(&P.hist16[(size_t)am * 65536 + (b >> 16)], 1u);
                atomicAdd(&P.ghist8[am * 256 + (b >> 24)], 1u);
            }
        }

        // bank histogram: LDS-privatized coarse, global fine
        int nbch = N >> 2;
        for (int j = gtid; j < nbch; j += gsz) {
            int4 y4 = *(const int4*)(P.labels + j * 4);
            float4 e4 = *(const float4*)(P.ent_bank + j * 4);
            unsigned b;
            b = __float_as_uint(e4.x);
            atomicAdd(&P.hist16[(size_t)y4.x * 65536 + (b >> 16)], 1u);
            atomicAdd(&sm.p1.h8[y4.x * 256 + (b >> 24)], 1u);
            b = __float_as_uint(e4.y);
            atomicAdd(&P.hist16[(size_t)y4.y * 65536 + (b >> 16)], 1u);
            atomicAdd(&sm.p1.h8[y4.y * 256 + (b >> 24)], 1u);
            b = __float_as_uint(e4.z);
            atomicAdd(&P.hist16[(size_t)y4.z * 65536 + (b >> 16)], 1u);
            atomicAdd(&sm.p1.h8[y4.z * 256 + (b >> 24)], 1u);
            b = __float_as_uint(e4.w);
            atomicAdd(&P.hist16[(size_t)y4.w * 65536 + (b >> 16)], 1u);
            atomicAdd(&sm.p1.h8[y4.w * 256 + (b >> 24)], 1u);
        }
        if (bid == 0) {   // bank tail (N % 4)
            for (int i = (nbch << 2) + tid; i < N; i += 256) {
                int y = P.labels[i];
                unsigned b = __float_as_uint(P.ent_bank[i]);
                atomicAdd(&P.hist16[(size_t)y * 65536 + (b >> 16)], 1u);
                atomicAdd(&P.ghist8[y * 256 + (b >> 24)], 1u);
            }
        }
        __syncthreads();
        for (int i = tid; i < C * 256; i += 256) {
            unsigned v = sm.p1.h8[i];
            if (v) atomicAdd(&P.ghist8[i], v);
        }
    }
    __threadfence(); grid.sync(); __threadfence();

    // ================= P2: pick (redundant per block) + compact ============
    {
        int K = P.fk[0];
        for (int c = wave; c < C; c += 4) {
            uint4 g0 = *(const uint4*)(P.ghist8 + c * 256 + lane * 4);
            unsigned h[4] = { g0.x, g0.y, g0.z, g0.w };
            int chunk, e1; unsigned total;
            wave_rank256(h, K, lane, &chunk, &e1, &total);
            if ((int)total <= K) {
                if (lane == 0) { sm.p2.done_s[c] = 1; sm.p2.krem_s[c] = 0;
                                 sm.p2.pfx16[c] = 0xFFFFFFFFu; }
                continue;
            }
            int K2 = K - e1;
            uint4 g1 = *(const uint4*)(P.hist16 + (size_t)c * 65536 + chunk * 256 + lane * 4);
            unsigned h2[4] = { g1.x, g1.y, g1.z, g1.w };
            int bin, e2; unsigned tot2;
            wave_rank256(h2, K2, lane, &bin, &e2, &tot2);
            if (lane == 0) {
                sm.p2.done_s[c] = 0;
                sm.p2.pfx16[c] = (unsigned)(chunk * 256 + bin);
                sm.p2.krem_s[c] = K2 - e2;
            }
        }
        if (tid < C) sm.p2.lcnt[tid] = 0;
        __syncthreads();
        if (bid == 0 && tid < C) P.krem_g[tid] = sm.p2.krem_s[tid];

        int nchunk = NT >> 2;          // gsz (65536) >= nchunk (26024)
        int4 y4; uint4 b4; int i0 = gtid << 2; int vn = 0;
        if (gtid < nchunk) {
            vn = 4;
            if (i0 + 4 <= N) {
                y4 = *(const int4*)(P.labels + i0);
                float4 e = *(const float4*)(P.ent_bank + i0);
                b4 = make_uint4(__float_as_uint(e.x), __float_as_uint(e.y),
                                __float_as_uint(e.z), __float_as_uint(e.w));
            } else if (i0 >= N) {
                y4 = *(const int4*)(P.yhat + (i0 - N));
                float4 e = *(const float4*)(P.ent_new + (i0 - N));
                b4 = make_uint4(__float_as_uint(e.x), __float_as_uint(e.y),
                                __float_as_uint(e.z), __float_as_uint(e.w));
            } else {
                int ys[4]; unsigned bs[4];
                for (int k = 0; k < 4; ++k) {
                    int i = i0 + k;
                    ys[k] = (i < N) ? P.labels[i] : P.yhat[i - N];
                    bs[k] = __float_as_uint((i < N) ? P.ent_bank[i] : P.ent_new[i - N]);
                }
                y4 = make_int4(ys[0], ys[1], ys[2], ys[3]);
                b4 = make_uint4(bs[0], bs[1], bs[2], bs[3]);
            }
        }
        int y_t = 0; unsigned b_t = 0; int i_t = 0; int have_t = 0;
        int tail0 = nchunk << 2;
        if (bid == 0 && tail0 + tid < NT) {
            i_t = tail0 + tid;
            y_t = (i_t < N) ? P.labels[i_t] : P.yhat[i_t - N];
            b_t = __float_as_uint((i_t < N) ? P.ent_bank[i_t] : P.ent_new[i_t - N]);
            have_t = 1;
        }
        auto each = [&](auto&& g) {
            if (vn > 0) { g(y4.x, b4.x, i0 + 0); g(y4.y, b4.y, i0 + 1);
                          g(y4.z, b4.z, i0 + 2); g(y4.w, b4.w, i0 + 3); }
            if (have_t) g(y_t, b_t, i_t);
        };

        each([&](int y, unsigned b, int i) {
            (void)i;
            unsigned t16 = b >> 16;
            if (sm.p2.done_s[y] || t16 < sm.p2.pfx16[y]) atomicAdd(&sm.p2.lcnt[y], 1);
        });
        __syncthreads();
        if (tid == 0) {
            int run = 0;
            for (int c = 0; c < C; ++c) { sm.p2.lofs[c] = run; run += sm.p2.lcnt[c]; }
        }
        __syncthreads();
        if (tid < C) {
            int m = sm.p2.lcnt[tid];
            sm.p2.gbase[tid] = m ? atomicAdd(&P.cnt_g[tid * PAD], m) : 0;
            sm.p2.lput[tid] = sm.p2.lofs[tid];
        }
        __syncthreads();
        each([&](int y, unsigned b, int i) {
            unsigned t16 = b >> 16;
            if (sm.p2.done_s[y] || t16 < sm.p2.pfx16[y]) {
                int p = atomicAdd(&sm.p2.lput[y], 1);
                sm.p2.l_list[p] = i;
            } else if (t16 == sm.p2.pfx16[y]) {
                unsigned q = atomicAdd(&P.ccnt_g[y * PAD], 1u);
                if (q < CANDCAP) { P.candb[y * CANDCAP + q] = b;
                                   P.candi[y * CANDCAP + q] = i; }
            }
        });
        __syncthreads();
        for (int c = 0; c < C; ++c) {
            int m = sm.p2.lcnt[c], base = sm.p2.gbase[c], off = sm.p2.lofs[c];
            int lim = CAP - base; if (m > lim) m = lim;   // safety clamp
            for (int t = tid; t < m; t += 256)
                P.list[c * CAP + base + t] = sm.p2.l_list[off + t];
        }
    }
    __threadfence(); grid.sync(); __threadfence();

    // ================= P3: exact (bits,index) tie-break -> list2 ===========
    if (bid < C) {
        int c = bid;
        int Kr = P.krem_g[c];
        int n = (int)min(P.ccnt_g[c * PAD], (unsigned)CANDCAP);
        if (Kr > 0 && n > 0) {
            for (int j = tid; j < n; j += 256) {
                sm.p3.cb[j] = __hip_atomic_load(&P.candb[c * CANDCAP + j],
                                  __ATOMIC_RELAXED, __HIP_MEMORY_SCOPE_AGENT);
                sm.p3.ci[j] = __hip_atomic_load(&P.candi[c * CANDCAP + j],
                                  __ATOMIC_RELAXED, __HIP_MEMORY_SCOPE_AGENT);
            }
            __syncthreads();
            for (int j = tid; j < n; j += 256) {
                unsigned bj = sm.p3.cb[j]; int ij = sm.p3.ci[j];
                int r = 0;
                for (int k = 0; k < n; ++k) {
                    unsigned bk = sm.p3.cb[k]; int ik = sm.p3.ci[k];
                    r += (bk < bj || (bk == bj && ik < ij)) ? 1 : 0;
                }
                if (r < Kr) P.list2[c * CANDCAP + r] = ij;
            }
        }
        if (tid == 0) P.s2cnt[c] = (Kr > 0) ? min(Kr, n) : 0;
    }
    __threadfence(); grid.sync(); __threadfence();

    // ================= P4: per-class normalized-row accumulate =============
    {
        int c = bid % C;
        int q = bid / C;
        int nch = (GRID - c + C - 1) / C;
        int s = min(P.cnt_g[c * PAD], CAP);
        int R = (s + nch - 1) / nch;
        int start = q * R;
        int end = min(start + R, s);
        float a0 = 0.f, a1 = 0.f, a2 = 0.f, a3 = 0.f;
        float a4 = 0.f, a5 = 0.f, a6 = 0.f, a7 = 0.f;
        auto add_row = [&](int r) {
            const float* x = (r < N) ? (P.supports + (size_t)r * D)
                                     : (P.feature + (size_t)(r - N) * D);
            float4 pp = *(const float4*)(x + lane * 8);
            float4 qq = *(const float4*)(x + lane * 8 + 4);
            float ss = pp.x * pp.x + pp.y * pp.y + pp.z * pp.z + pp.w * pp.w +
                       qq.x * qq.x + qq.y * qq.y + qq.z * qq.z + qq.w * qq.w;
            for (int m = 32; m; m >>= 1) ss += __shfl_xor(ss, m, 64);
            float inv = 1.f / fmaxf(sqrtf(ss), 1e-12f);
            a0 += pp.x * inv; a1 += pp.y * inv; a2 += pp.z * inv; a3 += pp.w * inv;
            a4 += qq.x * inv; a5 += qq.y * inv; a6 += qq.z * inv; a7 += qq.w * inv;
        };
        const int* lp = P.list + c * CAP;
        for (int j = start + wave; j < end; j += 4) add_row(lp[j]);
        if (q == 0) {
            int s2 = P.s2cnt[c];
            for (int j = wave; j < s2; j += 4) add_row(P.list2[c * CANDCAP + j]);
        }
        *(float4*)&sm.p4.wsum[wave][lane * 8]     = make_float4(a0, a1, a2, a3);
        *(float4*)&sm.p4.wsum[wave][lane * 8 + 4] = make_float4(a4, a5, a6, a7);
        __syncthreads();
        for (int i = tid; i < D; i += 256) {
            float t = sm.p4.wsum[0][i] + sm.p4.wsum[1][i] +
                      sm.p4.wsum[2][i] + sm.p4.wsum[3][i];
            if (t != 0.f) atomicAdd(&P.Wc[c * D + i], t);
        }
    }
    __threadfence(); grid.sync(); __threadfence();

    // ================= P5: column-normalize + output GEMV (2 halves) =======
    {
        for (int c = wave; c < C; c += 4) {
            const float* w = P.Wc + c * D + lane * 8;
            float ss = 0.f;
            for (int k = 0; k < 8; ++k) ss += w[k] * w[k];
            for (int m = 32; m; m >>= 1) ss += __shfl_xor(ss, m, 64);
            if (lane == 0) sm.p5.inv_s[c] = 1.f / fmaxf(sqrtf(ss), 1e-12f);
        }
        __syncthreads();
        for (int half = 0; half < 2; ++half) {
            int c0 = half * 9, c1 = (half == 0) ? 9 : C;
            int nc = c1 - c0;
            for (int i = tid; i < nc * D; i += 256)
                sm.p5.w_s[i] = P.Wc[c0 * D + i] * sm.p5.inv_s[c0 + i / D];
            __syncthreads();
            for (int row = gwave; row < B; row += nwave) {
                const float* f = P.feature + (size_t)row * D;
                float4 f0 = *(const float4*)(f + lane * 8);
                float4 f1 = *(const float4*)(f + lane * 8 + 4);
                for (int c = 0; c < nc; ++c) {
                    const float* w = sm.p5.w_s + c * D + lane * 8;
                    float s = f0.x * w[0] + f0.y * w[1] + f0.z * w[2] + f0.w * w[3] +
                              f1.x * w[4] + f1.y * w[5] + f1.z * w[6] + f1.w * w[7];
                    for (int m = 32; m; m >>= 1) s += __shfl_xor(s, m, 64);
                    if (lane == 0) P.out[(size_t)row * C + c0 + c] = s;
                }
            }
            __syncthreads();
        }
    }
}

// ===========================================================================
// ==================  FALLBACK: R4 MULTI-KERNEL (verbatim)  =================
// ===========================================================================
__global__ __launch_bounds__(256) void k_front(
    const float* __restrict__ feature, const float* __restrict__ clf_w,
    const float* __restrict__ clf_b, const float* __restrict__ ent_bank,
    const int* __restrict__ labels, float* __restrict__ ent_new,
    int* __restrict__ yhat, unsigned* __restrict__ hist16,
    unsigned* __restrict__ ghist8, int N, int B)
{
    __shared__ float w_s[C * D];
    __shared__ float b_s[32];
    int tid = threadIdx.x;
    for (int i = tid; i < C * D; i += 256) w_s[i] = clf_w[i];
    if (tid < C) b_s[tid] = clf_b[tid];
    __syncthreads();
    int wave = tid >> 6, lane = tid & 63;
    int row = blockIdx.x * 4 + wave;
    if (row < B) {
        const float* f = feature + (size_t)row * D;
        float4 f0 = *(const float4*)(f + lane * 8);
        float4 f1 = *(const float4*)(f + lane * 8 + 4);
        double p[C];
        for (int c = 0; c < C; ++c) {
            const float* w = w_s + c * D + lane * 8;
            double s = (double)f0.x * w[0] + (double)f0.y * w[1] +
                       (double)f0.z * w[2] + (double)f0.w * w[3] +
                       (double)f1.x * w[4] + (double)f1.y * w[5] +
                       (double)f1.z * w[6] + (double)f1.w * w[7];
            for (int m = 32; m; m >>= 1) s += __shfl_xor(s, m, 64);
            p[c] = s + (double)b_s[c];
        }
        if (lane == 0) {
            double mx = p[0]; int am = 0;
            for (int c = 1; c < C; ++c) if (p[c] > mx) { mx = p[c]; am = c; }
            double Z = 0.0, S = 0.0;
            for (int c = 0; c < C; ++c) {
                double e = exp(p[c] - mx);
                Z += e; S += e * (p[c] - mx);
            }
            float ent = (float)(log(Z) - S / Z);
            ent_new[row] = ent;
            yhat[row] = am;
            unsigned b = __float_as_uint(ent);
            atomicAdd(&hist16[(size_t)am * 65536 + (b >> 16)], 1u);
            atomicAdd(&ghist8[am * 256 + (b >> 24)], 1u);
        }
    }
    int gtid = blockIdx.x * 256 + tid;
    int nchunk = N >> 2;
    if (gtid < nchunk) {
        int4 y4 = *(const int4*)(labels + gtid * 4);
        float4 e4 = *(const float4*)(ent_bank + gtid * 4);
        unsigned b;
        b = __float_as_uint(e4.x);
        atomicAdd(&hist16[(size_t)y4.x * 65536 + (b >> 16)], 1u);
        atomicAdd(&ghist8[y4.x * 256 + (b >> 24)], 1u);
        b = __float_as_uint(e4.y);
        atomicAdd(&hist16[(size_t)y4.y * 65536 + (b >> 16)], 1u);
        atomicAdd(&ghist8[y4.y * 256 + (b >> 24)], 1u);
        b = __float_as_uint(e4.z);
        atomicAdd(&hist16[(size_t)y4.z * 65536 + (b >> 16)], 1u);
        atomicAdd(&ghist8[y4.z * 256 + (b >> 24)], 1u);
        b = __float_as_uint(e4.w);
        atomicAdd(&hist16[(size_t)y4.w * 65536 + (b >> 16)], 1u);
        atomicAdd(&ghist8[y4.w * 256 + (b >> 24)], 1u);
    }
    if (blockIdx.x == 0) {
        for (int i = (nchunk << 2) + tid; i < N; i += 256) {
            int y = labels[i];
            unsigned b = __float_as_uint(ent_bank[i]);
            atomicAdd(&hist16[(size_t)y * 65536 + (b >> 16)], 1u);
            atomicAdd(&ghist8[y * 256 + (b >> 24)], 1u);
        }
    }
}

__global__ __launch_bounds__(256) void k_compact(
    const float* __restrict__ ent_bank, const int* __restrict__ labels,
    const float* __restrict__ ent_new, const int* __restrict__ yhat,
    const unsigned* __restrict__ ghist8, const unsigned* __restrict__ hist16,
    const int* __restrict__ fk, int* __restrict__ krem_g,
    int* __restrict__ cnt_g, int* __restrict__ list,
    unsigned* __restrict__ ccnt_g, unsigned* __restrict__ candb,
    int* __restrict__ candi, int N, int B)
{
    __shared__ unsigned pfx16[C];
    __shared__ int krem_s[C];
    __shared__ int done_s[C];
    __shared__ int lcnt[C], lofs[C], lput[C], gbase[C];
    __shared__ int l_list[1312];

    int tid = threadIdx.x, wave = tid >> 6, lane = tid & 63;
    int K = fk[0];
    for (int c = wave; c < C; c += 4) {
        uint4 g0 = *(const uint4*)(ghist8 + c * 256 + lane * 4);
        unsigned h[4] = { g0.x, g0.y, g0.z, g0.w };
        int chunk, e1; unsigned total;
        wave_rank256(h, K, lane, &chunk, &e1, &total);
        if ((int)total <= K) {
            if (lane == 0) { done_s[c] = 1; krem_s[c] = 0; pfx16[c] = 0xFFFFFFFFu; }
            continue;
        }
        int K2 = K - e1;
        uint4 g1 = *(const uint4*)(hist16 + (size_t)c * 65536 + chunk * 256 + lane * 4);
        unsigned h2[4] = { g1.x, g1.y, g1.z, g1.w };
        int bin, e2; unsigned tot2;
        wave_rank256(h2, K2, lane, &bin, &e2, &tot2);
        if (lane == 0) {
            done_s[c] = 0;
            pfx16[c] = (unsigned)(chunk * 256 + bin);
            krem_s[c] = K2 - e2;
        }
    }
    if (tid < C) lcnt[tid] = 0;
    __syncthreads();
    if (blockIdx.x == 0 && tid < C) krem_g[tid] = krem_s[tid];

    int NT = N + B;
    int nchunk = NT >> 2;
    int gtid = blockIdx.x * 256 + tid;
    int4 y4; uint4 b4; int i0 = gtid << 2; int vn = 0;
    if (gtid < nchunk) {
        vn = 4;
        if (i0 + 4 <= N) {
            y4 = *(const int4*)(labels + i0);
            float4 e = *(const float4*)(ent_bank + i0);
            b4 = make_uint4(__float_as_uint(e.x), __float_as_uint(e.y),
                            __float_as_uint(e.z), __float_as_uint(e.w));
        } else if (i0 >= N) {
            y4 = *(const int4*)(yhat + (i0 - N));
            float4 e = *(const float4*)(ent_new + (i0 - N));
            b4 = make_uint4(__float_as_uint(e.x), __float_as_uint(e.y),
                            __float_as_uint(e.z), __float_as_uint(e.w));
        } else {
            int ys[4]; unsigned bs[4];
            for (int k = 0; k < 4; ++k) {
                int i = i0 + k;
                ys[k] = (i < N) ? labels[i] : yhat[i - N];
                bs[k] = __float_as_uint((i < N) ? ent_bank[i] : ent_new[i - N]);
            }
            y4 = make_int4(ys[0], ys[1], ys[2], ys[3]);
            b4 = make_uint4(bs[0], bs[1], bs[2], bs[3]);
        }
    }
    int y_t = 0; unsigned b_t = 0; int i_t = 0; int have_t = 0;
    int tail0 = nchunk << 2;
    if (blockIdx.x == 0 && tail0 + tid < NT) {
        i_t = tail0 + tid;
        y_t = (i_t < N) ? labels[i_t] : yhat[i_t - N];
        b_t = __float_as_uint((i_t < N) ? ent_bank[i_t] : ent_new[i_t - N]);
        have_t = 1;
    }
    auto each = [&](auto&& g) {
        if (vn > 0) { g(y4.x, b4.x, i0 + 0); g(y4.y, b4.y, i0 + 1);
                      g(y4.z, b4.z, i0 + 2); g(y4.w, b4.w, i0 + 3); }
        if (have_t) g(y_t, b_t, i_t);
    };
    each([&](int y, unsigned b, int i) {
        (void)i;
        unsigned t16 = b >> 16;
        if (done_s[y] || t16 < pfx16[y]) atomicAdd(&lcnt[y], 1);
    });
    __syncthreads();
    if (tid == 0) {
        int run = 0;
        for (int c = 0; c < C; ++c) { lofs[c] = run; run += lcnt[c]; }
    }
    __syncthreads();
    if (tid < C) {
        int m = lcnt[tid];
        gbase[tid] = m ? atomicAdd(&cnt_g[tid * PAD], m) : 0;
        lput[tid] = lofs[tid];
    }
    __syncthreads();
    each([&](int y, unsigned b, int i) {
        unsigned t16 = b >> 16;
        if (done_s[y] || t16 < pfx16[y]) {
            int p = atomicAdd(&lput[y], 1);
            l_list[p] = i;
        } else if (t16 == pfx16[y]) {
            unsigned q = atomicAdd(&ccnt_g[y * PAD], 1u);
            if (q < CANDCAP) { candb[y * CANDCAP + q] = b; candi[y * CANDCAP + q] = i; }
        }
    });
    __syncthreads();
    for (int c = 0; c < C; ++c) {
        int m = lcnt[c], base = gbase[c], off = lofs[c];
        int lim = CAP - base; if (m > lim) m = lim;
        for (int t = tid; t < m; t += 256)
            list[c * CAP + base + t] = l_list[off + t];
    }
}

__global__ __launch_bounds__(256) void k_accum(
    const float* __restrict__ supports, const float* __restrict__ feature,
    const int* __restrict__ list, const int* __restrict__ cnt_g,
    const unsigned* __restrict__ ccnt_g, const unsigned* __restrict__ candb,
    const int* __restrict__ candi, const int* __restrict__ krem_g,
    float* __restrict__ Wc, int N)
{
    __shared__ float wsum[4][D];
    __shared__ unsigned cb_s[CANDCAP];
    __shared__ int ci_s[CANDCAP];
    __shared__ int win[CANDCAP];
    __shared__ int wn_s;

    int c = blockIdx.y;
    int s = min(cnt_g[c * PAD], CAP);
    int nch = gridDim.x;
    int R = (s + nch - 1) / nch;
    int start = blockIdx.x * R;
    int end = min(start + R, s);
    int lane = threadIdx.x & 63, wave = threadIdx.x >> 6;
    float a0 = 0.f, a1 = 0.f, a2 = 0.f, a3 = 0.f;
    float a4 = 0.f, a5 = 0.f, a6 = 0.f, a7 = 0.f;
    auto add_row = [&](int r) {
        const float* x = (r < N) ? (supports + (size_t)r * D)
                                 : (feature + (size_t)(r - N) * D);
        float4 p = *(const float4*)(x + lane * 8);
        float4 q = *(const float4*)(x + lane * 8 + 4);
        float ss = p.x * p.x + p.y * p.y + p.z * p.z + p.w * p.w +
                   q.x * q.x + q.y * q.y + q.z * q.z + q.w * q.w;
        for (int m = 32; m; m >>= 1) ss += __shfl_xor(ss, m, 64);
        float inv = 1.f / fmaxf(sqrtf(ss), 1e-12f);
        a0 += p.x * inv; a1 += p.y * inv; a2 += p.z * inv; a3 += p.w * inv;
        a4 += q.x * inv; a5 += q.y * inv; a6 += q.z * inv; a7 += q.w * inv;
    };
    for (int j = start + wave; j < end; j += 4) add_row(list[c * CAP + j]);
    if (blockIdx.x == 0) {
        int n = (int)min(ccnt_g[c * PAD], (unsigned)CANDCAP);
        int Kr = krem_g[c];
        if (n > 0 && Kr > 0) {
            if (threadIdx.x == 0) wn_s = 0;
            for (int j = threadIdx.x; j < n; j += 256) {
                cb_s[j] = candb[c * CANDCAP + j];
                ci_s[j] = candi[c * CANDCAP + j];
            }
            __syncthreads();
            for (int j = threadIdx.x; j < n; j += 256) {
                unsigned bj = cb_s[j]; int ij = ci_s[j];
                int r = 0;
                for (int k = 0; k < n; ++k) {
                    unsigned bk = cb_s[k]; int ik = ci_s[k];
                    r += (bk < bj || (bk == bj && ik < ij)) ? 1 : 0;
                }
                if (r < Kr) { int pos = atomicAdd(&wn_s, 1); win[pos] = ij; }
            }
            __syncthreads();
            int wn = wn_s;
            for (int j = wave; j < wn; j += 4) add_row(win[j]);
        }
    }
    *(float4*)&wsum[wave][lane * 8]     = make_float4(a0, a1, a2, a3);
    *(float4*)&wsum[wave][lane * 8 + 4] = make_float4(a4, a5, a6, a7);
    __syncthreads();
    for (int i = threadIdx.x; i < D; i += 256) {
        float t = wsum[0][i] + wsum[1][i] + wsum[2][i] + wsum[3][i];
        if (t != 0.f) atomicAdd(&Wc[c * D + i], t);
    }
}

__global__ __launch_bounds__(256) void k_out(
    const float* __restrict__ feature, const float* __restrict__ Wc,
    float* __restrict__ out, int B)
{
    __shared__ float w_s[C * D];
    __shared__ float inv_s[32];
    int tid = threadIdx.x;
    for (int i = tid; i < C * D; i += 256) w_s[i] = Wc[i];
    __syncthreads();
    int wave = tid >> 6, lane = tid & 63;
    for (int c = wave; c < C; c += 4) {
        const float* w = w_s + c * D + lane * 8;
        float ss = 0.f;
        for (int k = 0; k < 8; ++k) ss += w[k] * w[k];
        for (int m = 32; m; m >>= 1) ss += __shfl_xor(ss, m, 64);
        if (lane == 0) inv_s[c] = 1.f / fmaxf(sqrtf(ss), 1e-12f);
    }
    __syncthreads();
    for (int row = blockIdx.x * 4 + wave; row < B; row += gridDim.x * 4) {
        const float* f = feature + (size_t)row * D;
        float4 f0 = *(const float4*)(f + lane * 8);
        float4 f1 = *(const float4*)(f + lane * 8 + 4);
        for (int c = 0; c < C; ++c) {
            const float* w = w_s + c * D + lane * 8;
            float s = f0.x * w[0] + f0.y * w[1] + f0.z * w[2] + f0.w * w[3] +
                      f1.x * w[4] + f1.y * w[5] + f1.z * w[6] + f1.w * w[7];
            for (int m = 32; m; m >>= 1) s += __shfl_xor(s, m, 64);
            if (lane == 0) out[(size_t)row * C + c] = s * inv_s[c];
        }
    }
}

// ---------------------------------------------------------------------------
extern "C" void kernel_launch(void* const* d_in, const int* in_sizes, int n_in,
                              void* d_out, int out_size, void* d_ws, size_t ws_size,
                              hipStream_t stream)
{
    (void)n_in; (void)out_size; (void)ws_size;
    const float* feature  = (const float*)d_in[0];
    const float* clf_w    = (const float*)d_in[1];
    const float* clf_b    = (const float*)d_in[2];
    const float* supports = (const float*)d_in[3];
    const float* ent_bank = (const float*)d_in[4];
    const int*   labels   = (const int*)d_in[5];
    const int*   fk       = (const int*)d_in[6];
    int B  = in_sizes[0] / D;
    int N  = in_sizes[4];
    int NT = N + B;

    char* ws = (char*)d_ws;
    size_t o = 0;
    auto align256 = [&](size_t x) { return (x + 255) & ~(size_t)255; };
    // ---- zeroed by one memset ----
    unsigned* hist16  = (unsigned*)(ws + o); o = align256(o + (size_t)C * 65536 * 4);
    unsigned* ghist8  = (unsigned*)(ws + o); o = align256(o + (size_t)C * 256 * 4);
    float*    Wc      = (float*)(ws + o);    o = align256(o + (size_t)C * D * 4);
    int*      cnt_g   = (int*)(ws + o);      o = align256(o + (size_t)C * PAD * 4);
    unsigned* ccnt_g  = (unsigned*)(ws + o); o = align256(o + (size_t)C * PAD * 4);
    size_t zero_bytes = o;
    // ---- always fully written before read ----
    float*    ent_new = (float*)(ws + o);    o = align256(o + (size_t)B * 4);
    int*      yhat    = (int*)(ws + o);      o = align256(o + (size_t)B * 4);
    int*      krem_g  = (int*)(ws + o);      o = align256(o + 32 * 4);
    int*      s2cnt   = (int*)(ws + o);      o = align256(o + 32 * 4);
    int*      list    = (int*)(ws + o);      o = align256(o + (size_t)C * CAP * 4);
    int*      list2   = (int*)(ws + o);      o = align256(o + (size_t)C * CANDCAP * 4);
    unsigned* candb   = (unsigned*)(ws + o); o = align256(o + (size_t)C * CANDCAP * 4);
    int*      candi   = (int*)(ws + o);      o = align256(o + (size_t)C * CANDCAP * 4);
    float*    out     = (float*)d_out;

    hipMemsetAsync(ws, 0, zero_bytes, stream);

    KParams P = { feature, clf_w, clf_b, supports, ent_bank, labels, fk,
                  ent_new, yhat, hist16, ghist8, Wc,
                  cnt_g, ccnt_g, krem_g, s2cnt,
                  list, list2, candb, candi, out, N, B };
    void* args[] = { (void*)&P };
    hipError_t e = hipLaunchCooperativeKernel((const void*)k_fused, dim3(GRID),
                                              dim3(256), args, 0, stream);
    if (e != hipSuccess) {
        // -------- fallback: proven R4 multi-kernel pipeline --------
        int cb = (B + 3) / 4; if (cb > 1024) cb = 1024;
        int fb = cb; int bankb = ((N >> 2) + 255) / 256; if (bankb > fb) fb = bankb;
        int sgc = ((NT >> 2) + 255) / 256;
        k_front<<<fb, 256, 0, stream>>>(feature, clf_w, clf_b, ent_bank, labels,
                                        ent_new, yhat, hist16, ghist8, N, B);
        k_compact<<<sgc, 256, 0, stream>>>(ent_bank, labels, ent_new, yhat,
                                           ghist8, hist16, fk, krem_g,
                                           cnt_g, list, ccnt_g, candb, candi, N, B);
        k_accum<<<dim3(32, C), 256, 0, stream>>>(supports, feature, list, cnt_g,
                                                 ccnt_g, candb, candi, krem_g, Wc, N);
        k_out<<<cb, 256, 0, stream>>>(feature, Wc, out, B);
    }
}